// Round 2
// baseline (186.692 us; speedup 1.0000x reference)
//
#include <hip/hip_runtime.h>

#define BB 16
#define LL 2048
#define DD 768
#define KK 32
#define TILE 32
#define NEGI -1e30f

// ---------------- Kernel 1: per-token scores ----------------
// One wave per token: score[b,l] = dot(th[b,l,:], w) + b0, or -1e30 if masked.
__global__ __launch_bounds__(256) void scores_k(
    const float* __restrict__ th,
    const float* __restrict__ attn,
    const float* __restrict__ wp,
    const float* __restrict__ bp,
    float* __restrict__ scores) {
  const int lane = threadIdx.x & 63;
  const int wave = threadIdx.x >> 6;
  const int token = (blockIdx.x << 2) + wave;  // < B*L = 32768

  // 768 floats/row, 64 lanes -> 12 floats = 3 float4 per lane (48B, 16B-aligned)
  const float4* row = (const float4*)(th + (size_t)token * DD) + lane * 3;
  const float4* wr  = (const float4*)wp + lane * 3;

  float4 a0 = row[0], a1 = row[1], a2 = row[2];
  float4 w0 = wr[0],  w1 = wr[1],  w2 = wr[2];

  float acc = 0.f;
  acc = fmaf(a0.x, w0.x, acc); acc = fmaf(a0.y, w0.y, acc);
  acc = fmaf(a0.z, w0.z, acc); acc = fmaf(a0.w, w0.w, acc);
  acc = fmaf(a1.x, w1.x, acc); acc = fmaf(a1.y, w1.y, acc);
  acc = fmaf(a1.z, w1.z, acc); acc = fmaf(a1.w, w1.w, acc);
  acc = fmaf(a2.x, w2.x, acc); acc = fmaf(a2.y, w2.y, acc);
  acc = fmaf(a2.z, w2.z, acc); acc = fmaf(a2.w, w2.w, acc);

  #pragma unroll
  for (int o = 32; o > 0; o >>= 1) acc += __shfl_xor(acc, o, 64);

  if (lane == 0) {
    float s = acc + bp[0];
    scores[token] = (attn[token] >= 0.5f) ? s : NEGI;
  }
}

// ---------------- Kernel 2: per-span softmax -> per-token weights ----------------
// One wave per (b,k): m, sum over span; write w[b,l] and span id[b,l]; sent flag.
__global__ __launch_bounds__(64) void spanprep_k(
    const int* __restrict__ sps,
    const int* __restrict__ spe,
    const float* __restrict__ scores,
    float* __restrict__ wbuf,
    int* __restrict__ idbuf,
    float* __restrict__ sent) {
  const int bk = blockIdx.x;          // b*K + k
  const int b = bk >> 5;              // K = 32
  const int k = bk & 31;
  const int lane = threadIdx.x;

  int s0 = min(max(sps[bk], 0), LL);
  int e0 = min(max(spe[bk], 0), LL);

  const float* sc = scores + (size_t)b * LL;

  float m = NEGI;
  for (int l = s0 + lane; l < e0; l += 64) m = fmaxf(m, sc[l]);
  #pragma unroll
  for (int o = 32; o > 0; o >>= 1) m = fmaxf(m, __shfl_xor(m, o, 64));

  float ss = 0.f;
  for (int l = s0 + lane; l < e0; l += 64) {
    float v = sc[l];
    ss += (v > -1e29f) ? __expf(v - m) : 0.f;
  }
  #pragma unroll
  for (int o = 32; o > 0; o >>= 1) ss += __shfl_xor(ss, o, 64);

  const float inv = (ss > 0.f) ? (1.0f / ss) : 0.f;

  for (int l = s0 + lane; l < e0; l += 64) {
    float v = sc[l];
    wbuf[(size_t)b * LL + l] = (v > -1e29f) ? (__expf(v - m) * inv) : 0.f;
    idbuf[(size_t)b * LL + l] = k;   // spans are disjoint -> no write races
  }

  if (lane == 0 && ss > 0.f) sent[bk] = 1.0f;  // d_out pre-zeroed
}

// ---------------- Kernel 3: segmented weighted sum over fixed L-tiles ----------------
// grid (B, L/TILE, 3 chunks of 256 dims); block = 1 wave; lane owns 4 dims (float4).
__global__ __launch_bounds__(64) void pool_k(
    const float* __restrict__ th,
    const float* __restrict__ wbuf,
    const int* __restrict__ idbuf,
    float* __restrict__ Hout) {
  const int b = blockIdx.x;
  const int tile0 = blockIdx.y * TILE;
  const int chunk = blockIdx.z;
  const int lane = threadIdx.x;

  __shared__ float lw[TILE];
  __shared__ int lid[TILE];
  if (lane < TILE) {
    lw[lane]  = wbuf[(size_t)b * LL + tile0 + lane];
    lid[lane] = idbuf[(size_t)b * LL + tile0 + lane];
  }
  __syncthreads();

  const float4* base = (const float4*)(th + (size_t)b * LL * DD + chunk * 256) + lane;

  float4 acc = make_float4(0.f, 0.f, 0.f, 0.f);
  int cur = lid[0];

  for (int t = 0; t < TILE; ++t) {
    const int id = lid[t];     // wave-uniform
    const float wt = lw[t];
    if (id != cur) {           // span boundary: flush accumulator
      if (cur >= 0) {
        float* o = Hout + ((size_t)(b * KK + cur) * DD) + chunk * 256 + (lane << 2);
        atomicAdd(o + 0, acc.x); atomicAdd(o + 1, acc.y);
        atomicAdd(o + 2, acc.z); atomicAdd(o + 3, acc.w);
      }
      acc = make_float4(0.f, 0.f, 0.f, 0.f);
      cur = id;
    }
    if (wt != 0.f) {           // skip gap/masked tokens (wave-uniform branch)
      float4 v = base[(size_t)(tile0 + t) * (DD / 4)];
      acc.x = fmaf(wt, v.x, acc.x);
      acc.y = fmaf(wt, v.y, acc.y);
      acc.z = fmaf(wt, v.z, acc.z);
      acc.w = fmaf(wt, v.w, acc.w);
    }
  }
  if (cur >= 0) {
    float* o = Hout + ((size_t)(b * KK + cur) * DD) + chunk * 256 + (lane << 2);
    atomicAdd(o + 0, acc.x); atomicAdd(o + 1, acc.y);
    atomicAdd(o + 2, acc.z); atomicAdd(o + 3, acc.w);
  }
}

extern "C" void kernel_launch(void* const* d_in, const int* in_sizes, int n_in,
                              void* d_out, int out_size, void* d_ws, size_t ws_size,
                              hipStream_t stream) {
  const float* th   = (const float*)d_in[0];  // [B,L,D] fp32
  const float* attn = (const float*)d_in[1];  // [B,L]   fp32
  const int*   sps  = (const int*)d_in[2];    // [B,K]
  const int*   spe  = (const int*)d_in[3];    // [B,K]
  const float* wp   = (const float*)d_in[4];  // [D]     fp32
  const float* bp   = (const float*)d_in[5];  // [1]     fp32

  float* Hout = (float*)d_out;                    // [B,K,D] then sent [B,K]
  float* sent = Hout + (size_t)BB * KK * DD;

  float* scores = (float*)d_ws;                   // B*L fp32   (128 KB)
  float* wbuf   = scores + (size_t)BB * LL;       // B*L fp32   (128 KB)
  int*   idbuf  = (int*)(wbuf + (size_t)BB * LL); // B*L int32  (128 KB)

  // d_out / d_ws are poisoned 0xAA before every call — re-init every call.
  hipMemsetAsync(d_out, 0, (size_t)out_size * sizeof(float), stream);
  hipMemsetAsync(wbuf, 0, (size_t)BB * LL * sizeof(float), stream);
  hipMemsetAsync(idbuf, 0xFF, (size_t)BB * LL * sizeof(int), stream);  // id = -1

  scores_k<<<dim3((BB * LL) / 4), dim3(256), 0, stream>>>(th, attn, wp, bp, scores);
  spanprep_k<<<dim3(BB * KK), dim3(64), 0, stream>>>(sps, spe, scores, wbuf, idbuf, sent);
  pool_k<<<dim3(BB, LL / TILE, 3), dim3(64), 0, stream>>>(th, wbuf, idbuf, Hout);
}

// Round 3
// 183.145 us; speedup vs baseline: 1.0194x; 1.0194x over previous
//
#include <hip/hip_runtime.h>

#define BB 16
#define LL 2048
#define DD 768
#define KK 32
#define TILE 32
#define NEGI -1e30f

// ---------------- Kernel 1: per-token scores + weight-buffer init ----------------
// One wave per token: score[b,l] = dot(th[b,l,:], w) + b0, or -1e30 if masked.
// Also initializes wbuf (0) and idbuf (-1) for this token, replacing two memsets.
__global__ __launch_bounds__(256) void scores_k(
    const float* __restrict__ th,
    const float* __restrict__ attn,
    const float* __restrict__ wp,
    const float* __restrict__ bp,
    float* __restrict__ scores,
    float* __restrict__ wbuf,
    int* __restrict__ idbuf) {
  const int lane = threadIdx.x & 63;
  const int wave = threadIdx.x >> 6;
  const int token = (blockIdx.x << 2) + wave;  // < B*L = 32768

  // 768 floats/row, 64 lanes -> 12 floats = 3 float4 per lane (48B, 16B-aligned)
  const float4* row = (const float4*)(th + (size_t)token * DD) + lane * 3;
  const float4* wr  = (const float4*)wp + lane * 3;

  float4 a0 = row[0], a1 = row[1], a2 = row[2];
  float4 w0 = wr[0],  w1 = wr[1],  w2 = wr[2];

  float acc = 0.f;
  acc = fmaf(a0.x, w0.x, acc); acc = fmaf(a0.y, w0.y, acc);
  acc = fmaf(a0.z, w0.z, acc); acc = fmaf(a0.w, w0.w, acc);
  acc = fmaf(a1.x, w1.x, acc); acc = fmaf(a1.y, w1.y, acc);
  acc = fmaf(a1.z, w1.z, acc); acc = fmaf(a1.w, w1.w, acc);
  acc = fmaf(a2.x, w2.x, acc); acc = fmaf(a2.y, w2.y, acc);
  acc = fmaf(a2.z, w2.z, acc); acc = fmaf(a2.w, w2.w, acc);

  #pragma unroll
  for (int o = 32; o > 0; o >>= 1) acc += __shfl_xor(acc, o, 64);

  if (lane == 0) {
    float s = acc + bp[0];
    scores[token] = (attn[token] >= 0.5f) ? s : NEGI;
    wbuf[token]   = 0.f;   // gap/default weight (spanprep_k overwrites in-span)
    idbuf[token]  = -1;    // gap/default span id
  }
}

// ---------------- Kernel 2: per-span softmax -> per-token weights ----------------
// One wave per (b,k): m, sum over span; write w[b,l] and span id[b,l]; sent flag.
__global__ __launch_bounds__(64) void spanprep_k(
    const int* __restrict__ sps,
    const int* __restrict__ spe,
    const float* __restrict__ scores,
    float* __restrict__ wbuf,
    int* __restrict__ idbuf,
    float* __restrict__ sent) {
  const int bk = blockIdx.x;          // b*K + k
  const int b = bk >> 5;              // K = 32
  const int k = bk & 31;
  const int lane = threadIdx.x;

  int s0 = min(max(sps[bk], 0), LL);
  int e0 = min(max(spe[bk], 0), LL);

  const float* sc = scores + (size_t)b * LL;

  float m = NEGI;
  for (int l = s0 + lane; l < e0; l += 64) m = fmaxf(m, sc[l]);
  #pragma unroll
  for (int o = 32; o > 0; o >>= 1) m = fmaxf(m, __shfl_xor(m, o, 64));

  float ss = 0.f;
  for (int l = s0 + lane; l < e0; l += 64) {
    float v = sc[l];
    ss += (v > -1e29f) ? __expf(v - m) : 0.f;
  }
  #pragma unroll
  for (int o = 32; o > 0; o >>= 1) ss += __shfl_xor(ss, o, 64);

  const float inv = (ss > 0.f) ? (1.0f / ss) : 0.f;

  for (int l = s0 + lane; l < e0; l += 64) {
    float v = sc[l];
    wbuf[(size_t)b * LL + l] = (v > -1e29f) ? (__expf(v - m) * inv) : 0.f;
    idbuf[(size_t)b * LL + l] = k;   // spans are disjoint -> no write races
  }

  if (lane == 0 && ss > 0.f) sent[bk] = 1.0f;  // d_out pre-zeroed
}

// ---------------- Kernel 3: segmented weighted sum over fixed L-tiles ----------------
// grid (B, L/TILE, 3 chunks of 256 dims); block = 1 wave; lane owns 4 dims (float4).
__global__ __launch_bounds__(64) void pool_k(
    const float* __restrict__ th,
    const float* __restrict__ wbuf,
    const int* __restrict__ idbuf,
    float* __restrict__ Hout) {
  const int b = blockIdx.x;
  const int tile0 = blockIdx.y * TILE;
  const int chunk = blockIdx.z;
  const int lane = threadIdx.x;

  __shared__ float lw[TILE];
  __shared__ int lid[TILE];
  if (lane < TILE) {
    lw[lane]  = wbuf[(size_t)b * LL + tile0 + lane];
    lid[lane] = idbuf[(size_t)b * LL + tile0 + lane];
  }
  __syncthreads();

  const float4* base = (const float4*)(th + (size_t)b * LL * DD + chunk * 256) + lane;

  float4 acc = make_float4(0.f, 0.f, 0.f, 0.f);
  int cur = lid[0];

  #pragma unroll 4
  for (int t = 0; t < TILE; ++t) {
    const int id = lid[t];     // wave-uniform
    const float wt = lw[t];
    if (id != cur) {           // span boundary: flush accumulator
      if (cur >= 0) {
        float* o = Hout + ((size_t)(b * KK + cur) * DD) + chunk * 256 + (lane << 2);
        atomicAdd(o + 0, acc.x); atomicAdd(o + 1, acc.y);
        atomicAdd(o + 2, acc.z); atomicAdd(o + 3, acc.w);
      }
      acc = make_float4(0.f, 0.f, 0.f, 0.f);
      cur = id;
    }
    if (wt != 0.f) {           // skip gap/masked tokens (wave-uniform branch)
      float4 v = base[(size_t)(tile0 + t) * (DD / 4)];
      acc.x = fmaf(wt, v.x, acc.x);
      acc.y = fmaf(wt, v.y, acc.y);
      acc.z = fmaf(wt, v.z, acc.z);
      acc.w = fmaf(wt, v.w, acc.w);
    }
  }
  if (cur >= 0) {
    float* o = Hout + ((size_t)(b * KK + cur) * DD) + chunk * 256 + (lane << 2);
    atomicAdd(o + 0, acc.x); atomicAdd(o + 1, acc.y);
    atomicAdd(o + 2, acc.z); atomicAdd(o + 3, acc.w);
  }
}

extern "C" void kernel_launch(void* const* d_in, const int* in_sizes, int n_in,
                              void* d_out, int out_size, void* d_ws, size_t ws_size,
                              hipStream_t stream) {
  const float* th   = (const float*)d_in[0];  // [B,L,D] fp32
  const float* attn = (const float*)d_in[1];  // [B,L]   fp32
  const int*   sps  = (const int*)d_in[2];    // [B,K]
  const int*   spe  = (const int*)d_in[3];    // [B,K]
  const float* wp   = (const float*)d_in[4];  // [D]     fp32
  const float* bp   = (const float*)d_in[5];  // [1]     fp32

  float* Hout = (float*)d_out;                    // [B,K,D] then sent [B,K]
  float* sent = Hout + (size_t)BB * KK * DD;

  float* scores = (float*)d_ws;                   // B*L fp32   (128 KB)
  float* wbuf   = scores + (size_t)BB * LL;       // B*L fp32   (128 KB)
  int*   idbuf  = (int*)(wbuf + (size_t)BB * LL); // B*L int32  (128 KB)

  // d_out is poisoned 0xAA before every call — zero it (atomic targets + sent).
  hipMemsetAsync(d_out, 0, (size_t)out_size * sizeof(float), stream);

  scores_k<<<dim3((BB * LL) / 4), dim3(256), 0, stream>>>(
      th, attn, wp, bp, scores, wbuf, idbuf);
  spanprep_k<<<dim3(BB * KK), dim3(64), 0, stream>>>(sps, spe, scores, wbuf, idbuf, sent);
  pool_k<<<dim3(BB, LL / TILE, 3), dim3(64), 0, stream>>>(th, wbuf, idbuf, Hout);
}